// Round 1
// baseline (137.371 us; speedup 1.0000x reference)
//
#include <hip/hip_runtime.h>

// Terrain3D — gather formulation, v2.
// Changes vs v1:
//  * tile 8x4x16 (was 4x4x32): less z-axis waste (covered 34 vs 50 voxels),
//    pairs/particle 47.3 -> 38.0, atomics 217K -> 156K.
//  * per-particle LDS record = 32 floats {kx[8], em[4], ky[4], kz[16]}:
//    inner loop = 2 broadcast ds_read_b128 + 2 ds_read_b32 per 4 voxels
//    (was 4 ds_read_b32 per 2 voxels + a global lst->meta chain).
//  * emotions staged in LDS: no global loads in the inner loop.
//  * counts padded to 1 per 128B line: no atomic false sharing across XCDs.
// ws layout (floats): [0, 5*G3) = H,E grids; then int counts[NTILES*CSTR];
// then int lists[NTILES*CAP]; then float4 meta[2*N] ({gx,gy,gz,omega},{m0..m3}).

namespace {
constexpr int   G      = 128;
constexpr int   G3     = G * G * G;
constexpr int   NE     = 4;
constexpr int   RAD    = 9;            // max(2, int(3*0.05*128/2)) = 9
constexpr float SIG    = 0.05f * (float)G * 0.5f;  // 3.2
constexpr float INV2S2 = 1.0f / (2.0f * SIG * SIG);
constexpr float ETA    = 0.01f;
constexpr float A_H    = 0.002f;
constexpr float A_E    = 0.001f;
constexpr float LEAK   = 5e-5f;

// tile geometry: 8 x 4 x 16 voxels (axis2 fastest in memory)
constexpr int T0 = 8, T1 = 4, T2 = 16;
constexpr int NT0 = G / T0, NT1 = G / T1, NT2 = G / T2;   // 16, 32, 8
constexpr int NTILES = NT0 * NT1 * NT2;                   // 4096
constexpr int CAP  = 88;   // interior mean ~44.3 pairs/tile; 6.6 sigma tail
constexpr int PSTR = 32;   // floats per particle in LDS table
constexpr int CSTR = 32;   // ints per counter slot (128B line padding)
}

__device__ __forceinline__ int clampi(int v, int lo, int hi) {
    return min(max(v, lo), hi);
}

// ---------------------------------------------------------------------------
// 1) bin + meta: one WAVE per particle. Lane 0 writes the particle meta;
//    lanes cover the <=4x6x3=72 candidate tiles of the bbox (1 atomic each).
// ---------------------------------------------------------------------------
__global__ void __launch_bounds__(256) bin_meta_kernel(
        const float* __restrict__ pos, const float* __restrict__ inten,
        const float4* __restrict__ emo4,
        int* __restrict__ counts, int* __restrict__ lists,
        float4* __restrict__ meta, int N) {
    const int p    = blockIdx.x * 4 + (threadIdx.x >> 6);
    const int lane = threadIdx.x & 63;
    if (p >= N) return;

    const float gx = (pos[p * 3 + 0] + 1.0f) * 0.5f * (float)(G - 1);
    const float gy = (pos[p * 3 + 1] + 1.0f) * 0.5f * (float)(G - 1);
    const float gz = (pos[p * 3 + 2] + 1.0f) * 0.5f * (float)(G - 1);
    const int c0 = clampi((int)floorf(gx), 0, G - 1);
    const int c1 = clampi((int)floorf(gy), 0, G - 1);
    const int c2 = clampi((int)floorf(gz), 0, G - 1);

    if (lane == 0) {
        meta[2 * p]     = make_float4(gx, gy, gz, inten[p] * ETA);
        meta[2 * p + 1] = emo4[p];
    }

    const int l0 = max(c0 - RAD, 0) >> 3, h0 = min(c0 + RAD, G - 1) >> 3;
    const int l1 = max(c1 - RAD, 0) >> 2, h1 = min(c1 + RAD, G - 1) >> 2;
    const int l2 = max(c2 - RAD, 0) >> 4, h2 = min(c2 + RAD, G - 1) >> 4;
    const int n0 = h0 - l0, n1 = h1 - l1, n2 = h2 - l2;  // inclusive spans - 1

    for (int s = lane; s < 72; s += 64) {          // fixed 4x6x3 slot grid
        const int a  = s / 18;        // 0..3  axis0
        const int r  = s - a * 18;
        const int b  = r / 3;         // 0..5  axis1
        const int cs = r - b * 3;     // 0..2  axis2
        if (a <= n0 && b <= n1 && cs <= n2) {
            const int t = ((l0 + a) * NT1 + (l1 + b)) * NT2 + (l2 + cs);
            const int slot = atomicAdd(&counts[t * CSTR], 1);
            if (slot < CAP) lists[t * CAP + slot] = p;
        }
    }
}

// ---------------------------------------------------------------------------
// 2) gather: one block (128 thr = 2 waves) per 8x4x16 tile. Build a 32-float
//    record per particle in LDS: kx[8] (omega folded), em[4], ky[4], kz[16].
//    Inner loop per (thread, particle): 2 broadcast b128 + 2 b32 LDS reads,
//    25 VALU, updates 4 voxels x 5 channels. No global access in the loop.
// ---------------------------------------------------------------------------
__global__ void __launch_bounds__(128) gather_kernel(
        const float4* __restrict__ meta,
        const float* __restrict__ H0, const float* __restrict__ E0,
        const int* __restrict__ counts, const int* __restrict__ lists,
        float* __restrict__ ws) {
    const int tile = blockIdx.x;
    const int t2 = tile & (NT2 - 1);
    const int t1 = (tile >> 3) & (NT1 - 1);
    const int t0 = tile >> 8;
    const int tid = threadIdx.x;

    __shared__ __align__(16) float tab[CAP * PSTR];   // 11264 B

    const int cnt = min(counts[tile * CSTR], CAP);
    const int* __restrict__ lst = lists + tile * CAP;
    const int b0 = t0 * T0, b1 = t1 * T1, b2 = t2 * T2;

    // ---- build records: 32 entries per particle ----
    for (int t = tid; t < cnt * PSTR; t += 128) {
        const int n = t >> 5;
        const int s = t & 31;
        const int p = lst[n];
        float v;
        if (s >= 8 && s < 12) {                       // emotions copy
            const float4 me = meta[2 * p + 1];
            const int q = s - 8;
            v = (q == 0) ? me.x : (q == 1) ? me.y : (q == 2) ? me.z : me.w;
        } else {
            const float4 mg = meta[2 * p];
            float g; int base, off;
            if (s < 8)       { g = mg.x; base = b0; off = s;      }  // kx
            else if (s < 16) { g = mg.y; base = b1; off = s - 12; }  // ky
            else             { g = mg.z; base = b2; off = s - 16; }  // kz
            const int cc = clampi((int)floorf(g), 0, G - 1);
            const int coord = base + off;
            const float d = (float)coord - g;
            v = (abs(coord - cc) <= RAD) ? __expf(-d * d * INV2S2) : 0.0f;
            if (s < 8) v *= mg.w;                     // fold omega into kx
        }
        tab[n * PSTR + s] = v;
    }
    __syncthreads();

    // ---- per-thread voxel ownership: 4 voxels along axis0 ----
    const int k  = tid & (T2 - 1);          // 0..15  axis2
    const int j  = (tid >> 4) & (T1 - 1);   // 0..3   axis1
    const int i4 = (tid >> 6) * 4;          // 0 or 4 axis0 (wave-uniform)

    const int x2 = b2 + k, x1 = b1 + j;
    const int flat0 = ((b0 + i4) * G + x1) * G + x2;

    float h[4], e[NE][4];
#pragma unroll
    for (int i = 0; i < 4; ++i) {
        h[i] = H0[flat0 + i * G * G];
#pragma unroll
        for (int c = 0; c < NE; ++c) e[c][i] = E0[c * G3 + flat0 + i * G * G];
    }

    const float* __restrict__ tkx = tab + i4;        // 16B aligned
    const float* __restrict__ tky = tab + 12 + j;
    const float* __restrict__ tkz = tab + 16 + k;

    for (int n = 0; n < cnt; ++n) {
        const float4 kxv = *(const float4*)(tkx + n * PSTR);     // broadcast
        const float4 emv = *(const float4*)(tab + n * PSTR + 8); // broadcast
        const float  kyz = tky[n * PSTR] * tkz[n * PSTR];
        const float w0 = kxv.x * kyz, w1 = kxv.y * kyz,
                    w2 = kxv.z * kyz, w3 = kxv.w * kyz;
        h[0] += w0;  h[1] += w1;  h[2] += w2;  h[3] += w3;
        e[0][0] += w0 * emv.x; e[0][1] += w1 * emv.x;
        e[0][2] += w2 * emv.x; e[0][3] += w3 * emv.x;
        e[1][0] += w0 * emv.y; e[1][1] += w1 * emv.y;
        e[1][2] += w2 * emv.y; e[1][3] += w3 * emv.y;
        e[2][0] += w0 * emv.z; e[2][1] += w1 * emv.z;
        e[2][2] += w2 * emv.z; e[2][3] += w3 * emv.z;
        e[3][0] += w0 * emv.w; e[3][1] += w1 * emv.w;
        e[3][2] += w2 * emv.w; e[3][3] += w3 * emv.w;
    }

#pragma unroll
    for (int i = 0; i < 4; ++i) {
        ws[flat0 + i * G * G] = h[i];
#pragma unroll
        for (int c = 0; c < NE; ++c)
            ws[(c + 1) * G3 + flat0 + i * G * G] = e[c][i];
    }
}

// ---------------------------------------------------------------------------
// 3) fused step (leak + alpha*laplacian + relu) + trilinear sample.
//    8-way corner parallelism + shuffle reduction.
//    NOTE reference transpose: splat flattens (c0*G+c1)*G+c2 but sampling
//    reads vol[comp2][comp1][comp0] -> flat = comp2*G^2 + comp1*G + comp0.
// ---------------------------------------------------------------------------
__device__ __forceinline__ float stepped_at(const float* __restrict__ vol,
                                            int z, int y, int x,
                                            float addc, float alpha) {
    const int zm = max(z - 1, 0), zp = min(z + 1, G - 1);
    const int ym = max(y - 1, 0), yp = min(y + 1, G - 1);
    const int xm = max(x - 1, 0), xp = min(x + 1, G - 1);
    const float cv  = vol[(z * G + y) * G + x];
    const float lap = vol[(zm * G + y) * G + x] + vol[(zp * G + y) * G + x]
                    + vol[(z * G + ym) * G + x] + vol[(z * G + yp) * G + x]
                    + vol[(z * G + y) * G + xm] + vol[(z * G + y) * G + xp]
                    - 6.0f * cv;
    const float s = cv * (1.0f - LEAK) + addc + alpha * lap;
    return fmaxf(s, 0.0f);
}

__global__ void __launch_bounds__(256) sample_kernel(
        const float* __restrict__ sp, const float* __restrict__ ws,
        float* __restrict__ out, int n_out) {
    const int gt = blockIdx.x * blockDim.x + threadIdx.x;
    const int corner = gt & 7;
    const int o = gt >> 3;
    if (o >= n_out) return;
    const int c = o % 5;   // 0 = H, 1..4 = E
    const int p = o / 5;

    const float t0 = fminf(fmaxf((sp[p * 3 + 0] + 1.0f) * 0.5f * (float)(G - 1), 0.0f), (float)(G - 1));
    const float t1 = fminf(fmaxf((sp[p * 3 + 1] + 1.0f) * 0.5f * (float)(G - 1), 0.0f), (float)(G - 1));
    const float t2 = fminf(fmaxf((sp[p * 3 + 2] + 1.0f) * 0.5f * (float)(G - 1), 0.0f), (float)(G - 1));

    const int a0 = (int)floorf(t0);  const float f0 = t0 - (float)a0;
    const int a1 = (int)floorf(t1);  const float f1 = t1 - (float)a1;
    const int a2 = (int)floorf(t2);  const float f2 = t2 - (float)a2;
    const int b0 = min(a0 + 1, G - 1);
    const int b1 = min(a1 + 1, G - 1);
    const int b2 = min(a2 + 1, G - 1);

    const int d0 = corner & 1, d1 = (corner >> 1) & 1, d2 = corner >> 2;
    const int   x = d0 ? b0 : a0;          // comp0 -> fastest axis
    const int   y = d1 ? b1 : a1;          // comp1
    const int   z = d2 ? b2 : a2;          // comp2 -> slowest axis
    const float w = (d0 ? f0 : 1.0f - f0) * (d1 ? f1 : 1.0f - f1)
                  * (d2 ? f2 : 1.0f - f2);

    const float* vol  = ws + (size_t)c * G3;
    const float addc  = (c == 0) ? 0.0f : LEAK;
    const float alpha = (c == 0) ? A_H : A_E;

    float v = w * stepped_at(vol, z, y, x, addc, alpha);
    v += __shfl_xor(v, 1);
    v += __shfl_xor(v, 2);
    v += __shfl_xor(v, 4);
    if (corner == 0) out[o] = v;
}

// ---------------------------------------------------------------------------
extern "C" void kernel_launch(void* const* d_in, const int* in_sizes, int n_in,
                              void* d_out, int out_size, void* d_ws, size_t ws_size,
                              hipStream_t stream) {
    const float* positions   = (const float*)d_in[0];  // (N,3)
    const float* intensities = (const float*)d_in[1];  // (N,)
    const float* emotions    = (const float*)d_in[2];  // (N,4)
    const float* sample_pos  = (const float*)d_in[3];  // (B,T,3)
    const float* H0          = (const float*)d_in[4];  // (G,G,G)
    const float* E0          = (const float*)d_in[5];  // (4,G,G,G)
    float* ws  = (float*)d_ws;
    float* out = (float*)d_out;

    const int N = in_sizes[0] / 3;

    int*    counts = (int*)(ws + 5 * (size_t)G3);
    int*    lists  = counts + (size_t)NTILES * CSTR;
    float4* meta   = (float4*)(lists + (size_t)NTILES * CAP);

    hipMemsetAsync(counts, 0, (size_t)NTILES * CSTR * sizeof(int), stream);

    bin_meta_kernel<<<(N + 3) / 4, 256, 0, stream>>>(
        positions, intensities, (const float4*)emotions, counts, lists, meta, N);

    gather_kernel<<<NTILES, 128, 0, stream>>>(
        meta, H0, E0, counts, lists, ws);

    const int n_thr = out_size * 8;
    sample_kernel<<<(n_thr + 255) / 256, 256, 0, stream>>>(
        sample_pos, ws, out, out_size);
}

// Round 2
// 113.785 us; speedup vs baseline: 1.2073x; 1.2073x over previous
//
#include <hip/hip_runtime.h>

// Terrain3D — v3: fully fused analytic formulation. The grid is NEVER
// materialized. Key fact: with nonneg base grids the step's ReLU is provably
// inactive (1 - LEAK - 6*alpha > 0, splat >= 0), so sample∘step∘splat is
// LINEAR in the splat. Output = (trilinear+stencil of base H0/E0) +
// sum_p omega_p * separable-Gaussian contraction (18 exp per pair).
// ws layout: int counts[NTILES*CSTR]; int lists[NTILES*CAP]; float4 meta[2N].

namespace {
constexpr int   G      = 128;
constexpr int   G3     = G * G * G;
constexpr int   RAD    = 9;            // max(2, int(3*0.05*128/2)) = 9
constexpr float SIG    = 0.05f * (float)G * 0.5f;  // 3.2
constexpr float INV2S2 = 1.0f / (2.0f * SIG * SIG);
constexpr float ETA    = 0.01f;
constexpr float A_H    = 0.002f;
constexpr float A_E    = 0.001f;
constexpr float LEAK   = 5e-5f;

// tile geometry over array dims (dim0,dim1,dim2): 8 x 4 x 16
constexpr int T0 = 8, T1 = 4, T2 = 16;
constexpr int NT0 = G / T0, NT1 = G / T1, NT2 = G / T2;   // 16, 32, 8
constexpr int NTILES = NT0 * NT1 * NT2;                   // 4096
constexpr int CAP  = 96;   // mean ~52 with sample margins; 6.1 sigma tail
constexpr int CSTR = 32;   // ints per counter slot (128B line padding)
// list margins: sample needs voxels [cell-1, cell+2]; particle support RAD.
// particle cp must be kept if cp in [b - (RAD+1), b + T-1 + (RAD+2)].
}

__device__ __forceinline__ int clampi(int v, int lo, int hi) {
    return min(max(v, lo), hi);
}

// ---------------------------------------------------------------------------
// 1) bin + meta: one WAVE per particle; lanes cover <=4x7x3=84 candidate
//    tiles (expanded margins). Counters padded to 1/128B line.
// ---------------------------------------------------------------------------
__global__ void __launch_bounds__(256) bin_meta_kernel(
        const float* __restrict__ pos, const float* __restrict__ inten,
        const float4* __restrict__ emo4,
        int* __restrict__ counts, int* __restrict__ lists,
        float4* __restrict__ meta, int N) {
    const int p    = blockIdx.x * 4 + (threadIdx.x >> 6);
    const int lane = threadIdx.x & 63;
    if (p >= N) return;

    const float gx = (pos[p * 3 + 0] + 1.0f) * 0.5f * (float)(G - 1);
    const float gy = (pos[p * 3 + 1] + 1.0f) * 0.5f * (float)(G - 1);
    const float gz = (pos[p * 3 + 2] + 1.0f) * 0.5f * (float)(G - 1);
    const int c0 = clampi((int)floorf(gx), 0, G - 1);
    const int c1 = clampi((int)floorf(gy), 0, G - 1);
    const int c2 = clampi((int)floorf(gz), 0, G - 1);

    if (lane == 0) {
        meta[2 * p]     = make_float4(gx, gy, gz, inten[p] * ETA);
        meta[2 * p + 1] = emo4[p];
    }

    // tile-base windows: b0 in [c0-18, c0+10], b1 in [c1-14, c1+10],
    //                    b2 in [c2-26, c2+10]  (exact ceil/floor)
    const int t0lo = (max(c0 - 18, 0) + T0 - 1) >> 3;
    const int t0hi = min(c0 + 10, G - 1) >> 3;
    const int t1lo = (max(c1 - 14, 0) + T1 - 1) >> 2;
    const int t1hi = min(c1 + 10, G - 1) >> 2;
    const int t2lo = (max(c2 - 26, 0) + T2 - 1) >> 4;
    const int t2hi = min(c2 + 10, G - 1) >> 4;
    const int n0 = t0hi - t0lo, n1 = t1hi - t1lo, n2 = t2hi - t2lo;

    for (int s = lane; s < 84; s += 64) {          // fixed 4x7x3 slot grid
        const int a  = s / 21;        // 0..3  dim0
        const int r  = s - a * 21;
        const int b  = r / 3;         // 0..6  dim1
        const int cs = r - b * 3;     // 0..2  dim2
        if (a <= n0 && b <= n1 && cs <= n2) {
            const int t = ((t0lo + a) * NT1 + (t1lo + b)) * NT2 + (t2lo + cs);
            const int slot = atomicAdd(&counts[t * CSTR], 1);
            if (slot < CAP) lists[t * CAP + slot] = p;
        }
    }
}

// ---------------------------------------------------------------------------
// 2) fused step+sample directly from particle lists. One wave per sample.
//    NOTE reference transpose: splat flattens (c0*G+c1)*G+c2 but sampling
//    reads vol[comp2][comp1][comp0] -> array dim0 pairs sample comp2 with
//    particle gx; dim1: comp1<->gy; dim2 (fastest): comp0<->gz.
// ---------------------------------------------------------------------------
__device__ __forceinline__ float stepped_at(const float* __restrict__ vol,
                                            int z, int y, int x,
                                            float addc, float alpha) {
    const int zm = max(z - 1, 0), zp = min(z + 1, G - 1);
    const int ym = max(y - 1, 0), yp = min(y + 1, G - 1);
    const int xm = max(x - 1, 0), xp = min(x + 1, G - 1);
    const float cv  = vol[(z * G + y) * G + x];
    const float lap = vol[(zm * G + y) * G + x] + vol[(zp * G + y) * G + x]
                    + vol[(z * G + ym) * G + x] + vol[(z * G + yp) * G + x]
                    + vol[(z * G + y) * G + xm] + vol[(z * G + y) * G + xp]
                    - 6.0f * cv;
    return cv * (1.0f - LEAK) + addc + alpha * lap;   // ReLU provably inactive
}

// per-axis contraction: direct (2-tap trilinear) and laplacian (4-tap) of the
// particle Gaussian along one array axis. 6 exp evals (dup-safe at edges).
__device__ __forceinline__ void axis_eval(float g, int ia, int ib,
        int ma, int pa, int mb, int pb, float wa, float wb,
        float& dir, float& lap) {
    const int cp = clampi((int)floorf(g), 0, G - 1);
    auto kf = [&](int v) -> float {
        const float d = (float)v - g;
        const float e = __expf(-d * d * INV2S2);
        return (abs(v - cp) <= RAD) ? e : 0.0f;
    };
    const float ka = kf(ia), kb = kf(ib);
    lap = wa * (kf(ma) + kf(pa) - 2.0f * ka)
        + wb * (kf(mb) + kf(pb) - 2.0f * kb);
    dir = wa * ka + wb * kb;
}

__global__ void __launch_bounds__(256) fused_sample_kernel(
        const float* __restrict__ sp, const float4* __restrict__ meta,
        const int* __restrict__ counts, const int* __restrict__ lists,
        const float* __restrict__ H0, const float* __restrict__ E0,
        float* __restrict__ out, int n_samp) {
    const int wave = (blockIdx.x * blockDim.x + threadIdx.x) >> 6;
    const int lane = threadIdx.x & 63;
    if (wave >= n_samp) return;

    const float s0 = sp[wave * 3 + 0];
    const float s1 = sp[wave * 3 + 1];
    const float s2 = sp[wave * 3 + 2];
    // array dim0 (z) <- comp2, dim1 (y) <- comp1, dim2 (x) <- comp0
    const float uz = fminf(fmaxf((s2 + 1.0f) * 0.5f * (float)(G - 1), 0.0f), (float)(G - 1));
    const float uy = fminf(fmaxf((s1 + 1.0f) * 0.5f * (float)(G - 1), 0.0f), (float)(G - 1));
    const float ux = fminf(fmaxf((s0 + 1.0f) * 0.5f * (float)(G - 1), 0.0f), (float)(G - 1));
    const int za = (int)floorf(uz); const float fz = uz - (float)za;
    const int ya = (int)floorf(uy); const float fy = uy - (float)ya;
    const int xa = (int)floorf(ux); const float fx = ux - (float)xa;
    const int zb = min(za + 1, G - 1);
    const int yb = min(ya + 1, G - 1);
    const int xb = min(xa + 1, G - 1);

    // ---- base grids (general H0/E0): lanes 0..39, lane = c*8 + corner ----
    float bv = 0.0f;
    if (lane < 40) {
        const int c = lane >> 3, corner = lane & 7;
        const int d0 = corner & 1, d1 = (corner >> 1) & 1, d2 = corner >> 2;
        const int x = d0 ? xb : xa, y = d1 ? yb : ya, z = d2 ? zb : za;
        const float w = (d0 ? fx : 1.0f - fx) * (d1 ? fy : 1.0f - fy)
                      * (d2 ? fz : 1.0f - fz);
        const float* vol  = (c == 0) ? H0 : E0 + (size_t)(c - 1) * G3;
        const float addc  = (c == 0) ? 0.0f : LEAK;
        const float alpha = (c == 0) ? A_H : A_E;
        bv = w * stepped_at(vol, z, y, x, addc, alpha);
    }
    bv += __shfl_xor(bv, 1);   // reduce 8 corners within each 8-lane group
    bv += __shfl_xor(bv, 2);
    bv += __shfl_xor(bv, 4);

    // ---- splat functional over the tile's particle list ----
    const int tile = ((za >> 3) * NT1 + (ya >> 2)) * NT2 + (xa >> 4);
    const int cnt = min(counts[tile * CSTR], CAP);
    const int* __restrict__ lst = lists + tile * CAP;

    const int zma = max(za - 1, 0), zpa = min(za + 1, G - 1);
    const int zmb = max(zb - 1, 0), zpb = min(zb + 1, G - 1);
    const int yma = max(ya - 1, 0), ypa = min(ya + 1, G - 1);
    const int ymb = max(yb - 1, 0), ypb = min(yb + 1, G - 1);
    const int xma = max(xa - 1, 0), xpa = min(xa + 1, G - 1);
    const int xmb = max(xb - 1, 0), xpb = min(xb + 1, G - 1);
    const float wza = 1.0f - fz, wzb = fz;
    const float wya = 1.0f - fy, wyb = fy;
    const float wxa = 1.0f - fx, wxb = fx;

    float aH = 0.0f, aE0 = 0.0f, aE1 = 0.0f, aE2 = 0.0f, aE3 = 0.0f;
    for (int nb = lane; nb < cnt; nb += 64) {
        const int p = lst[nb];
        const float4 mg = meta[2 * p];        // gx, gy, gz, omega
        const float4 me = meta[2 * p + 1];    // emotions
        float dz_, lz_, dy_, ly_, dx_, lx_;
        axis_eval(mg.x, za, zb, zma, zpa, zmb, zpb, wza, wzb, dz_, lz_);
        axis_eval(mg.y, ya, yb, yma, ypa, ymb, ypb, wya, wyb, dy_, ly_);
        axis_eval(mg.z, xa, xb, xma, xpa, xmb, xpb, wxa, wxb, dx_, lx_);
        const float b3 = dz_ * dy_ * dx_;
        const float l3 = lz_ * dy_ * dx_ + dz_ * ly_ * dx_ + dz_ * dy_ * lx_;
        const float cH = mg.w * ((1.0f - LEAK) * b3 + A_H * l3);
        const float cE = mg.w * ((1.0f - LEAK) * b3 + A_E * l3);
        aH  += cH;
        aE0 += cE * me.x;  aE1 += cE * me.y;
        aE2 += cE * me.z;  aE3 += cE * me.w;
    }

#define RED64(v) { v += __shfl_xor(v, 1);  v += __shfl_xor(v, 2);  \
                   v += __shfl_xor(v, 4);  v += __shfl_xor(v, 8);  \
                   v += __shfl_xor(v, 16); v += __shfl_xor(v, 32); }
    RED64(aH) RED64(aE0) RED64(aE1) RED64(aE2) RED64(aE3)
#undef RED64

    const int  src   = (lane < 5) ? lane * 8 : 0;
    const float basec = __shfl(bv, src);
    const float sv = (lane == 0) ? aH  : (lane == 1) ? aE0
                   : (lane == 2) ? aE1 : (lane == 3) ? aE2 : aE3;
    if (lane < 5) out[wave * 5 + lane] = basec + sv;
}

// ---------------------------------------------------------------------------
extern "C" void kernel_launch(void* const* d_in, const int* in_sizes, int n_in,
                              void* d_out, int out_size, void* d_ws, size_t ws_size,
                              hipStream_t stream) {
    const float* positions   = (const float*)d_in[0];  // (N,3)
    const float* intensities = (const float*)d_in[1];  // (N,)
    const float* emotions    = (const float*)d_in[2];  // (N,4)
    const float* sample_pos  = (const float*)d_in[3];  // (B,T,3)
    const float* H0          = (const float*)d_in[4];  // (G,G,G)
    const float* E0          = (const float*)d_in[5];  // (4,G,G,G)
    float* out = (float*)d_out;

    const int N = in_sizes[0] / 3;

    int*    counts = (int*)d_ws;
    int*    lists  = counts + (size_t)NTILES * CSTR;
    float4* meta   = (float4*)(lists + (size_t)NTILES * CAP);

    hipMemsetAsync(counts, 0, (size_t)NTILES * CSTR * sizeof(int), stream);

    bin_meta_kernel<<<(N + 3) / 4, 256, 0, stream>>>(
        positions, intensities, (const float4*)emotions, counts, lists, meta, N);

    const int n_samp = out_size / 5;           // 5 channels per sample point
    fused_sample_kernel<<<(n_samp + 3) / 4, 256, 0, stream>>>(
        sample_pos, meta, counts, lists, H0, E0, out, n_samp);
}

// Round 3
// 112.254 us; speedup vs baseline: 1.2237x; 1.0136x over previous
//
#include <hip/hip_runtime.h>

// Terrain3D — v4: fused analytic formulation, overlapped phases.
//  K1 (merged): blocks [0,nbin) bin particles into tile lists (atomics,
//     latency-bound); blocks [nbin, nbin+nbase) compute the BASE-grid part
//     (trilinear of 7-pt-stencil-stepped H0/E0) and write out. The two
//     phases are independent -> co-resident, bin hides under base's HBM.
//  K2: splat functional add-only: out += sum_p omega_p * separable-Gaussian
//     contraction; 12 __expf per (sample,particle) (deduped taps).
// Linearity fact (unchanged from v3): ReLU in step is provably inactive for
// nonneg base + nonneg splat since 1-LEAK-6*alpha > 0, so
// sample∘step∘(base+splat) = [sample∘step∘base] + [analytic splat term].
// ws layout: int counts[NTILES*CSTR]; int lists[NTILES*CAP]; float4 meta[2N].

namespace {
constexpr int   G      = 128;
constexpr int   G3     = G * G * G;
constexpr int   RAD    = 9;            // max(2, int(3*0.05*128/2)) = 9
constexpr float SIG    = 0.05f * (float)G * 0.5f;  // 3.2
constexpr float INV2S2 = 1.0f / (2.0f * SIG * SIG);
constexpr float ETA    = 0.01f;
constexpr float A_H    = 0.002f;
constexpr float A_E    = 0.001f;
constexpr float LEAK   = 5e-5f;

// tile geometry over array dims (dim0,dim1,dim2): 8 x 4 x 16
constexpr int T0 = 8, T1 = 4, T2 = 16;
constexpr int NT0 = G / T0, NT1 = G / T1, NT2 = G / T2;   // 16, 32, 8
constexpr int NTILES = NT0 * NT1 * NT2;                   // 4096
constexpr int CAP  = 96;   // mean ~52 with sample margins; 6.1 sigma tail
constexpr int CSTR = 32;   // ints per counter slot (128B line padding)
}

__device__ __forceinline__ int clampi(int v, int lo, int hi) {
    return min(max(v, lo), hi);
}

// base-grid: stepped value at one voxel (ReLU inactive, addc folded here)
__device__ __forceinline__ float stepped_at(const float* __restrict__ vol,
                                            int z, int y, int x,
                                            float addc, float alpha) {
    const int zm = max(z - 1, 0), zp = min(z + 1, G - 1);
    const int ym = max(y - 1, 0), yp = min(y + 1, G - 1);
    const int xm = max(x - 1, 0), xp = min(x + 1, G - 1);
    const float cv  = vol[(z * G + y) * G + x];
    const float lap = vol[(zm * G + y) * G + x] + vol[(zp * G + y) * G + x]
                    + vol[(z * G + ym) * G + x] + vol[(z * G + yp) * G + x]
                    + vol[(z * G + y) * G + xm] + vol[(z * G + y) * G + xp]
                    - 6.0f * cv;
    return cv * (1.0f - LEAK) + addc + alpha * lap;
}

// ---------------------------------------------------------------------------
// K1: merged bin (blocks < nbin) + base sample (blocks >= nbin).
// ---------------------------------------------------------------------------
__global__ void __launch_bounds__(256) bin_base_kernel(
        const float* __restrict__ pos, const float* __restrict__ inten,
        const float4* __restrict__ emo4,
        int* __restrict__ counts, int* __restrict__ lists,
        float4* __restrict__ meta,
        const float* __restrict__ sp,
        const float* __restrict__ H0, const float* __restrict__ E0,
        float* __restrict__ out,
        int N, int nbin, int n_samp) {
    const int lane = threadIdx.x & 63;

    if ((int)blockIdx.x < nbin) {
        // ---------------- bin + meta: one wave per particle ----------------
        const int p = blockIdx.x * 4 + (threadIdx.x >> 6);
        if (p >= N) return;

        const float gx = (pos[p * 3 + 0] + 1.0f) * 0.5f * (float)(G - 1);
        const float gy = (pos[p * 3 + 1] + 1.0f) * 0.5f * (float)(G - 1);
        const float gz = (pos[p * 3 + 2] + 1.0f) * 0.5f * (float)(G - 1);
        const int c0 = clampi((int)floorf(gx), 0, G - 1);
        const int c1 = clampi((int)floorf(gy), 0, G - 1);
        const int c2 = clampi((int)floorf(gz), 0, G - 1);

        if (lane == 0) {
            meta[2 * p]     = make_float4(gx, gy, gz, inten[p] * ETA);
            meta[2 * p + 1] = emo4[p];
        }

        // tile-base windows: b0 in [c0-18,c0+10], b1 in [c1-14,c1+10],
        //                    b2 in [c2-26,c2+10]
        const int t0lo = (max(c0 - 18, 0) + T0 - 1) >> 3;
        const int t0hi = min(c0 + 10, G - 1) >> 3;
        const int t1lo = (max(c1 - 14, 0) + T1 - 1) >> 2;
        const int t1hi = min(c1 + 10, G - 1) >> 2;
        const int t2lo = (max(c2 - 26, 0) + T2 - 1) >> 4;
        const int t2hi = min(c2 + 10, G - 1) >> 4;
        const int n0 = t0hi - t0lo, n1 = t1hi - t1lo, n2 = t2hi - t2lo;

        for (int s = lane; s < 84; s += 64) {      // fixed 4x7x3 slot grid
            const int a  = s / 21;
            const int r  = s - a * 21;
            const int b  = r / 3;
            const int cs = r - b * 3;
            if (a <= n0 && b <= n1 && cs <= n2) {
                const int t = ((t0lo + a) * NT1 + (t1lo + b)) * NT2 + (t2lo + cs);
                const int slot = atomicAdd(&counts[t * CSTR], 1);
                if (slot < CAP) lists[t * CAP + slot] = p;
            }
        }
        return;
    }

    // ---------------- base sample: one wave per sample point ----------------
    const int w = (blockIdx.x - nbin) * 4 + (threadIdx.x >> 6);
    if (w >= n_samp) return;

    const float s0 = sp[w * 3 + 0];
    const float s1 = sp[w * 3 + 1];
    const float s2 = sp[w * 3 + 2];
    // array dim0 (z) <- comp2, dim1 (y) <- comp1, dim2 fastest (x) <- comp0
    const float uz = fminf(fmaxf((s2 + 1.0f) * 0.5f * (float)(G - 1), 0.0f), (float)(G - 1));
    const float uy = fminf(fmaxf((s1 + 1.0f) * 0.5f * (float)(G - 1), 0.0f), (float)(G - 1));
    const float ux = fminf(fmaxf((s0 + 1.0f) * 0.5f * (float)(G - 1), 0.0f), (float)(G - 1));
    const int za = (int)floorf(uz); const float fz = uz - (float)za;
    const int ya = (int)floorf(uy); const float fy = uy - (float)ya;
    const int xa = (int)floorf(ux); const float fx = ux - (float)xa;
    const int zb = min(za + 1, G - 1);
    const int yb = min(ya + 1, G - 1);
    const int xb = min(xa + 1, G - 1);

    float bv = 0.0f;
    if (lane < 40) {                      // lane = channel*8 + corner
        const int c = lane >> 3, corner = lane & 7;
        const int d0 = corner & 1, d1 = (corner >> 1) & 1, d2 = corner >> 2;
        const int x = d0 ? xb : xa, y = d1 ? yb : ya, z = d2 ? zb : za;
        const float wt = (d0 ? fx : 1.0f - fx) * (d1 ? fy : 1.0f - fy)
                       * (d2 ? fz : 1.0f - fz);
        const float* vol  = (c == 0) ? H0 : E0 + (size_t)(c - 1) * G3;
        const float addc  = (c == 0) ? 0.0f : LEAK;
        const float alpha = (c == 0) ? A_H : A_E;
        bv = wt * stepped_at(vol, z, y, x, addc, alpha);
    }
    bv += __shfl_xor(bv, 1);      // reduce 8 corners per 8-lane group
    bv += __shfl_xor(bv, 2);
    bv += __shfl_xor(bv, 4);
    if (lane < 40 && (lane & 7) == 0) out[w * 5 + (lane >> 3)] = bv;
}

// ---------------------------------------------------------------------------
// K2: splat functional, add-only. 4 exps per axis (deduped taps).
// dir = wa*k(ia) + wb*k(ib)
// lap = wa*(k(ma)+k(ib)-2k(ia)) + wb*(kmb+k(pb)-2k(ib)), kmb = ib>ia?k(ia):k(ma)
// ---------------------------------------------------------------------------
__device__ __forceinline__ void axis_eval4(float g, int ia, int ib,
        float wa, float wb, float& dir, float& lap) {
    const int cp = clampi((int)floorf(g), 0, G - 1);
    const int ma = max(ia - 1, 0);
    const int pb = min(ib + 1, G - 1);
    auto kf = [&](int v) -> float {
        const float d = (float)v - g;
        const float e = __expf(-d * d * INV2S2);
        return (abs(v - cp) <= RAD) ? e : 0.0f;
    };
    const float kma = kf(ma), ka = kf(ia), kb = kf(ib), kpb = kf(pb);
    const float kmb = (ib > ia) ? ka : kma;
    dir = wa * ka + wb * kb;
    lap = wa * (kma + kb - 2.0f * ka) + wb * (kmb + kpb - 2.0f * kb);
}

__global__ void __launch_bounds__(256) splat_add_kernel(
        const float* __restrict__ sp, const float4* __restrict__ meta,
        const int* __restrict__ counts, const int* __restrict__ lists,
        float* __restrict__ out, int n_samp) {
    const int w = (blockIdx.x * blockDim.x + threadIdx.x) >> 6;
    const int lane = threadIdx.x & 63;
    if (w >= n_samp) return;

    const float s0 = sp[w * 3 + 0];
    const float s1 = sp[w * 3 + 1];
    const float s2 = sp[w * 3 + 2];
    const float uz = fminf(fmaxf((s2 + 1.0f) * 0.5f * (float)(G - 1), 0.0f), (float)(G - 1));
    const float uy = fminf(fmaxf((s1 + 1.0f) * 0.5f * (float)(G - 1), 0.0f), (float)(G - 1));
    const float ux = fminf(fmaxf((s0 + 1.0f) * 0.5f * (float)(G - 1), 0.0f), (float)(G - 1));
    const int za = (int)floorf(uz); const float fz = uz - (float)za;
    const int ya = (int)floorf(uy); const float fy = uy - (float)ya;
    const int xa = (int)floorf(ux); const float fx = ux - (float)xa;
    const int zb = min(za + 1, G - 1);
    const int yb = min(ya + 1, G - 1);
    const int xb = min(xa + 1, G - 1);

    const int tile = ((za >> 3) * NT1 + (ya >> 2)) * NT2 + (xa >> 4);
    const int cnt = min(counts[tile * CSTR], CAP);
    const int* __restrict__ lst = lists + tile * CAP;

    const float wza = 1.0f - fz, wzb = fz;
    const float wya = 1.0f - fy, wyb = fy;
    const float wxa = 1.0f - fx, wxb = fx;

    float aH = 0.0f, aE0 = 0.0f, aE1 = 0.0f, aE2 = 0.0f, aE3 = 0.0f;
    for (int nb = lane; nb < cnt; nb += 64) {
        const int p = lst[nb];
        const float4 mg = meta[2 * p];        // gx, gy, gz, omega
        const float4 me = meta[2 * p + 1];    // emotions
        float dz_, lz_, dy_, ly_, dx_, lx_;
        axis_eval4(mg.x, za, zb, wza, wzb, dz_, lz_);  // particle gx <-> dim0
        axis_eval4(mg.y, ya, yb, wya, wyb, dy_, ly_);
        axis_eval4(mg.z, xa, xb, wxa, wxb, dx_, lx_);
        const float b3 = dz_ * dy_ * dx_;
        const float l3 = lz_ * dy_ * dx_ + dz_ * ly_ * dx_ + dz_ * dy_ * lx_;
        const float bl = (1.0f - LEAK) * b3;
        const float cH = mg.w * (bl + A_H * l3);
        const float cE = mg.w * (bl + A_E * l3);
        aH  += cH;
        aE0 += cE * me.x;  aE1 += cE * me.y;
        aE2 += cE * me.z;  aE3 += cE * me.w;
    }

#define RED64(v) { v += __shfl_xor(v, 1);  v += __shfl_xor(v, 2);  \
                   v += __shfl_xor(v, 4);  v += __shfl_xor(v, 8);  \
                   v += __shfl_xor(v, 16); v += __shfl_xor(v, 32); }
    RED64(aH) RED64(aE0) RED64(aE1) RED64(aE2) RED64(aE3)
#undef RED64

    if (lane < 5) {
        const float sv = (lane == 0) ? aH  : (lane == 1) ? aE0
                       : (lane == 2) ? aE1 : (lane == 3) ? aE2 : aE3;
        out[w * 5 + lane] += sv;
    }
}

// ---------------------------------------------------------------------------
extern "C" void kernel_launch(void* const* d_in, const int* in_sizes, int n_in,
                              void* d_out, int out_size, void* d_ws, size_t ws_size,
                              hipStream_t stream) {
    const float* positions   = (const float*)d_in[0];  // (N,3)
    const float* intensities = (const float*)d_in[1];  // (N,)
    const float* emotions    = (const float*)d_in[2];  // (N,4)
    const float* sample_pos  = (const float*)d_in[3];  // (B,T,3)
    const float* H0          = (const float*)d_in[4];  // (G,G,G)
    const float* E0          = (const float*)d_in[5];  // (4,G,G,G)
    float* out = (float*)d_out;

    const int N = in_sizes[0] / 3;
    const int n_samp = out_size / 5;       // 5 channels per sample point

    int*    counts = (int*)d_ws;
    int*    lists  = counts + (size_t)NTILES * CSTR;
    float4* meta   = (float4*)(lists + (size_t)NTILES * CAP);

    hipMemsetAsync(counts, 0, (size_t)NTILES * CSTR * sizeof(int), stream);

    const int nbin  = (N + 3) / 4;
    const int nbase = (n_samp + 3) / 4;
    bin_base_kernel<<<nbin + nbase, 256, 0, stream>>>(
        positions, intensities, (const float4*)emotions,
        counts, lists, meta, sample_pos, H0, E0, out, N, nbin, n_samp);

    splat_add_kernel<<<(n_samp + 3) / 4, 256, 0, stream>>>(
        sample_pos, meta, counts, lists, out, n_samp);
}

// Round 6
// 110.457 us; speedup vs baseline: 1.2437x; 1.0163x over previous
//
#include <hip/hip_runtime.h>

// Terrain3D — v5.1: analytic formulation, dependency-minimal schedule.
//   memset(counts)  ->  K_bin (lists/meta, ~3us)  ->  K_fused (base + splat).
// K_fused: one wave per sample. The 7-tap x 5-channel base-grid loads are
// issued FIRST (independent scattered loads, ~70 lines/sample); the splat
// particle loop (12 expf/pair, pure VALU on L2-resident lists/meta) runs
// while they are in flight; then the base stencil is combined.
// v5 bug fixed here: the final __shfl(bv, lane*8) was inside `if (lane<5)`;
// source lanes 8/16/24/32 were exec-masked off and ds_bpermute returned 0,
// dropping the base term for channels 1..4 (absmax ~= 1.0 = E base). The
// shuffle must be executed UNCONDITIONALLY by all lanes (as in v3).
// Linearity fact (v3): step's ReLU is provably inactive for nonneg base +
// nonneg splat (1-LEAK-6*alpha > 0), so
// sample∘step∘(base+splat) = [sample∘step∘base] + [analytic splat term].
// ws layout: int counts[NTILES*CSTR]; int lists[NTILES*CAP]; float4 meta[2N].

namespace {
constexpr int   G      = 128;
constexpr int   G3     = G * G * G;
constexpr int   RAD    = 9;            // max(2, int(3*0.05*128/2)) = 9
constexpr float SIG    = 0.05f * (float)G * 0.5f;  // 3.2
constexpr float INV2S2 = 1.0f / (2.0f * SIG * SIG);
constexpr float ETA    = 0.01f;
constexpr float A_H    = 0.002f;
constexpr float A_E    = 0.001f;
constexpr float LEAK   = 5e-5f;

// tile geometry over array dims (dim0,dim1,dim2): 8 x 4 x 16
constexpr int T0 = 8, T1 = 4, T2 = 16;
constexpr int NT0 = G / T0, NT1 = G / T1, NT2 = G / T2;   // 16, 32, 8
constexpr int NTILES = NT0 * NT1 * NT2;                   // 4096
constexpr int CAP  = 96;   // mean ~52 with sample margins; 6.1 sigma tail
constexpr int CSTR = 32;   // ints per counter slot (128B line padding)
}

__device__ __forceinline__ int clampi(int v, int lo, int hi) {
    return min(max(v, lo), hi);
}

// ---------------------------------------------------------------------------
// K_bin: one wave per particle; lanes cover <=4x7x3=84 candidate tiles
// (margins include the sample's [cell-1, cell+2] stencil extent).
// ---------------------------------------------------------------------------
__global__ void __launch_bounds__(256) bin_meta_kernel(
        const float* __restrict__ pos, const float* __restrict__ inten,
        const float4* __restrict__ emo4,
        int* __restrict__ counts, int* __restrict__ lists,
        float4* __restrict__ meta, int N) {
    const int p    = blockIdx.x * 4 + (threadIdx.x >> 6);
    const int lane = threadIdx.x & 63;
    if (p >= N) return;

    const float gx = (pos[p * 3 + 0] + 1.0f) * 0.5f * (float)(G - 1);
    const float gy = (pos[p * 3 + 1] + 1.0f) * 0.5f * (float)(G - 1);
    const float gz = (pos[p * 3 + 2] + 1.0f) * 0.5f * (float)(G - 1);
    const int c0 = clampi((int)floorf(gx), 0, G - 1);
    const int c1 = clampi((int)floorf(gy), 0, G - 1);
    const int c2 = clampi((int)floorf(gz), 0, G - 1);

    if (lane == 0) {
        meta[2 * p]     = make_float4(gx, gy, gz, inten[p] * ETA);
        meta[2 * p + 1] = emo4[p];
    }

    // tile-base windows: b0 in [c0-18,c0+10], b1 in [c1-14,c1+10],
    //                    b2 in [c2-26,c2+10]
    const int t0lo = (max(c0 - 18, 0) + T0 - 1) >> 3;
    const int t0hi = min(c0 + 10, G - 1) >> 3;
    const int t1lo = (max(c1 - 14, 0) + T1 - 1) >> 2;
    const int t1hi = min(c1 + 10, G - 1) >> 2;
    const int t2lo = (max(c2 - 26, 0) + T2 - 1) >> 4;
    const int t2hi = min(c2 + 10, G - 1) >> 4;
    const int n0 = t0hi - t0lo, n1 = t1hi - t1lo, n2 = t2hi - t2lo;

    for (int s = lane; s < 84; s += 64) {          // fixed 4x7x3 slot grid
        const int a  = s / 21;
        const int r  = s - a * 21;
        const int b  = r / 3;
        const int cs = r - b * 3;
        if (a <= n0 && b <= n1 && cs <= n2) {
            const int t = ((t0lo + a) * NT1 + (t1lo + b)) * NT2 + (t2lo + cs);
            const int slot = atomicAdd(&counts[t * CSTR], 1);
            if (slot < CAP) lists[t * CAP + slot] = p;
        }
    }
}

// ---------------------------------------------------------------------------
// per-axis Gaussian contraction: direct (2-tap trilinear) and laplacian
// (4-tap); 4 exps per axis (deduped taps; exact at edges via select).
// ---------------------------------------------------------------------------
__device__ __forceinline__ void axis_eval4(float g, int ia, int ib,
        float wa, float wb, float& dir, float& lap) {
    const int cp = clampi((int)floorf(g), 0, G - 1);
    const int ma = max(ia - 1, 0);
    const int pb = min(ib + 1, G - 1);
    auto kf = [&](int v) -> float {
        const float d = (float)v - g;
        const float e = __expf(-d * d * INV2S2);
        return (abs(v - cp) <= RAD) ? e : 0.0f;
    };
    const float kma = kf(ma), ka = kf(ia), kb = kf(ib), kpb = kf(pb);
    const float kmb = (ib > ia) ? ka : kma;
    dir = wa * ka + wb * kb;
    lap = wa * (kma + kb - 2.0f * ka) + wb * (kmb + kpb - 2.0f * kb);
}

// ---------------------------------------------------------------------------
// K_fused: one wave per sample point.
//   NOTE reference transpose: splat flattens (c0*G+c1)*G+c2 but sampling
//   reads vol[comp2][comp1][comp0] -> array dim0 (z) <-> sample comp2 and
//   particle gx; dim1 (y) <-> comp1/gy; dim2 fastest (x) <-> comp0/gz.
// ---------------------------------------------------------------------------
__global__ void __launch_bounds__(256) fused_kernel(
        const float* __restrict__ sp, const float4* __restrict__ meta,
        const int* __restrict__ counts, const int* __restrict__ lists,
        const float* __restrict__ H0, const float* __restrict__ E0,
        float* __restrict__ out, int n_samp) {
    const int w    = (blockIdx.x * blockDim.x + threadIdx.x) >> 6;
    const int lane = threadIdx.x & 63;
    if (w >= n_samp) return;

    const float s0 = sp[w * 3 + 0];
    const float s1 = sp[w * 3 + 1];
    const float s2 = sp[w * 3 + 2];
    const float uz = fminf(fmaxf((s2 + 1.0f) * 0.5f * (float)(G - 1), 0.0f), (float)(G - 1));
    const float uy = fminf(fmaxf((s1 + 1.0f) * 0.5f * (float)(G - 1), 0.0f), (float)(G - 1));
    const float ux = fminf(fmaxf((s0 + 1.0f) * 0.5f * (float)(G - 1), 0.0f), (float)(G - 1));
    const int za = (int)floorf(uz); const float fz = uz - (float)za;
    const int ya = (int)floorf(uy); const float fy = uy - (float)ya;
    const int xa = (int)floorf(ux); const float fx = ux - (float)xa;
    const int zb = min(za + 1, G - 1);
    const int yb = min(ya + 1, G - 1);
    const int xb = min(xa + 1, G - 1);

    // ---- phase 1: ISSUE base-grid loads (all 64 lanes; lanes>=40 get
    //      weight-0 duplicates of channel-4 lines -> L1 hits, no divergence)
    const int  craw   = lane >> 3;              // 0..7
    const int  corner = lane & 7;
    const bool bvalid = (craw < 5);
    const int  c      = min(craw, 4);
    const int d0 = corner & 1, d1 = (corner >> 1) & 1, d2 = corner >> 2;
    const int x = d0 ? xb : xa, y = d1 ? yb : ya, z = d2 ? zb : za;
    float wt = (d0 ? fx : 1.0f - fx) * (d1 ? fy : 1.0f - fy)
             * (d2 ? fz : 1.0f - fz);
    if (!bvalid) wt = 0.0f;
    const float* __restrict__ vol = (c == 0) ? H0 : E0 + (size_t)(c - 1) * G3;
    const float addc  = (c == 0) ? 0.0f : LEAK;
    const float alpha = (c == 0) ? A_H : A_E;

    const int zm = max(z - 1, 0), zp = min(z + 1, G - 1);
    const int ym = max(y - 1, 0), yp = min(y + 1, G - 1);
    const int xm = max(x - 1, 0), xp = min(x + 1, G - 1);
    const float cv  = vol[(z  * G + y ) * G + x ];
    const float n1v = vol[(zm * G + y ) * G + x ];
    const float n2v = vol[(zp * G + y ) * G + x ];
    const float n3v = vol[(z  * G + ym) * G + x ];
    const float n4v = vol[(z  * G + yp) * G + x ];
    const float n5v = vol[(z  * G + y ) * G + xm];
    const float n6v = vol[(z  * G + y ) * G + xp];

    // ---- phase 2: splat functional (VALU-heavy, hides under the loads) ----
    const int tile = ((za >> 3) * NT1 + (ya >> 2)) * NT2 + (xa >> 4);
    const int cnt = min(counts[tile * CSTR], CAP);
    const int* __restrict__ lst = lists + tile * CAP;

    const float wza = 1.0f - fz, wzb = fz;
    const float wya = 1.0f - fy, wyb = fy;
    const float wxa = 1.0f - fx, wxb = fx;

    float aH = 0.0f, aE0 = 0.0f, aE1 = 0.0f, aE2 = 0.0f, aE3 = 0.0f;
    for (int nb = lane; nb < cnt; nb += 64) {
        const int p = lst[nb];
        const float4 mg = meta[2 * p];        // gx, gy, gz, omega
        const float4 me = meta[2 * p + 1];    // emotions
        float dz_, lz_, dy_, ly_, dx_, lx_;
        axis_eval4(mg.x, za, zb, wza, wzb, dz_, lz_);  // particle gx <-> dim0
        axis_eval4(mg.y, ya, yb, wya, wyb, dy_, ly_);
        axis_eval4(mg.z, xa, xb, wxa, wxb, dx_, lx_);
        const float b3 = dz_ * dy_ * dx_;
        const float l3 = lz_ * dy_ * dx_ + dz_ * ly_ * dx_ + dz_ * dy_ * lx_;
        const float bl = (1.0f - LEAK) * b3;
        const float cH = mg.w * (bl + A_H * l3);
        const float cE = mg.w * (bl + A_E * l3);
        aH  += cH;
        aE0 += cE * me.x;  aE1 += cE * me.y;
        aE2 += cE * me.z;  aE3 += cE * me.w;
    }

#define RED64(v) { v += __shfl_xor(v, 1);  v += __shfl_xor(v, 2);  \
                   v += __shfl_xor(v, 4);  v += __shfl_xor(v, 8);  \
                   v += __shfl_xor(v, 16); v += __shfl_xor(v, 32); }
    RED64(aH) RED64(aE0) RED64(aE1) RED64(aE2) RED64(aE3)
#undef RED64

    // ---- phase 3: combine base stencil (loads have landed by now) ----
    const float lap = n1v + n2v + n3v + n4v + n5v + n6v - 6.0f * cv;
    float bv = wt * (cv * (1.0f - LEAK) + addc + alpha * lap);
    bv += __shfl_xor(bv, 1);      // reduce 8 corners per 8-lane group
    bv += __shfl_xor(bv, 2);
    bv += __shfl_xor(bv, 4);

    // cross-lane gather MUST be executed by all lanes (source lanes 8..32
    // need active EXEC bits for ds_bpermute) — v5's bug.
    const int   src   = (lane < 5) ? lane * 8 : 0;
    const float basec = __shfl(bv, src);

    if (lane < 5) {
        const float sv = (lane == 0) ? aH  : (lane == 1) ? aE0
                       : (lane == 2) ? aE1 : (lane == 3) ? aE2 : aE3;
        out[w * 5 + lane] = basec + sv;
    }
}

// ---------------------------------------------------------------------------
extern "C" void kernel_launch(void* const* d_in, const int* in_sizes, int n_in,
                              void* d_out, int out_size, void* d_ws, size_t ws_size,
                              hipStream_t stream) {
    const float* positions   = (const float*)d_in[0];  // (N,3)
    const float* intensities = (const float*)d_in[1];  // (N,)
    const float* emotions    = (const float*)d_in[2];  // (N,4)
    const float* sample_pos  = (const float*)d_in[3];  // (B,T,3)
    const float* H0          = (const float*)d_in[4];  // (G,G,G)
    const float* E0          = (const float*)d_in[5];  // (4,G,G,G)
    float* out = (float*)d_out;

    const int N = in_sizes[0] / 3;
    const int n_samp = out_size / 5;       // 5 channels per sample point

    int*    counts = (int*)d_ws;
    int*    lists  = counts + (size_t)NTILES * CSTR;
    float4* meta   = (float4*)(lists + (size_t)NTILES * CAP);

    hipMemsetAsync(counts, 0, (size_t)NTILES * CSTR * sizeof(int), stream);

    bin_meta_kernel<<<(N + 3) / 4, 256, 0, stream>>>(
        positions, intensities, (const float4*)emotions,
        counts, lists, meta, N);

    fused_kernel<<<(n_samp + 3) / 4, 256, 0, stream>>>(
        sample_pos, meta, counts, lists, H0, E0, out, n_samp);
}